// Round 6
// baseline (386.292 us; speedup 1.0000x reference)
//
#include <hip/hip_runtime.h>

// ============================================================================
// ContDecoder on MI355X — round 6: in-place activation buffer (2 blocks/CU)
// + manual B-prefetch ring.
//
// R5 diagnosis: VGPR=52 => compiler serialized B(L2)->MFMA per k-step; 8
// waves/CU could not hide ~300cyc loads (204us vs ~40us pipe floor). R6:
// (a) single 544-col activation buffer, overwritten in place after a barrier
//     (acc lives in registers across it) -> LDS 74.25 KB -> 2 blocks/CU,
//     16 waves/CU;
// (b) explicit register ring of B fragments, depth 4 k-steps, so 4 loads are
//     in flight per wave; __launch_bounds__(512,4) caps VGPR at 128.
//
// LDS per point (bf16): [xin 0..48 | buf 48..592], SROW=594 (x2B=1188,
// dword stride 297 odd -> clean bank spread). Chain: xin(37p48) ->W0->
// buf h0(516p544) ->W1-> buf[0,256) ->W2-> buf[0,128) ->W3-> [0,64) ->W4->
// [0,32) ->W5-> [0,16) ->W6-> out(2). K segments are exact multiples of 16,
// pad rows of packed W are zero, pad neurons get zero bias => exact zeros;
// buf cols [516,544) + xin[37,48) zero-inited once (poison guard).
// ============================================================================

#define NTH     512
#define NWAVES  8
#define MPTS    64               // 2 m-tiles of 32 points
#define SROW    594
#define BUF_OFF 48
#define NPOINTS (8 * 16384)
#define GRIDX   (NPOINTS / MPTS)     // 2048 blocks
#define LDSBYTES (MPTS * SROW * 2)   // 76032 B = 74.25 KB

typedef short          short8 __attribute__((ext_vector_type(8)));
typedef float          f32x16 __attribute__((ext_vector_type(16)));
typedef unsigned short u16;
typedef unsigned int   u32;

__device__ __forceinline__ u32 f2bf(float f) {
    u32 u = __builtin_bit_cast(u32, f);
    u += 0x7fffu + ((u >> 16) & 1u);        // round-to-nearest-even
    return u >> 16;
}

// ---------------------------------------------------------------------------
// Packed-weight geometry: 1KB fragments of 512 bf16. Fragment (l, nt, s):
// lane holds W[k = s*16 + (lane>>5)*8 + j][n = nt*32 + (lane&31)], j=0..7.
//   l : KHS  KS  NT   frag_base
//   0 :  0    3  17      0       (xin-only, K=48)
//   1 : 34   37   8     51
//   2 : 16   19   4    347
//   3 :  8   11   2    423
//   4 :  4    7   1    445
//   5 :  2    5   1    452
//   6 :  1    1   1    457     total 458 frags = 458 KB in d_ws
// ---------------------------------------------------------------------------
__constant__ int pk_base[8] = {0, 51, 347, 423, 445, 452, 457, 458};
__constant__ int pk_ks[7]   = {3, 37, 19, 11, 7, 5, 1};
__constant__ int pk_khs[7]  = {0, 34, 16, 8, 4, 2, 1};
__constant__ int pk_kact[7] = {0, 516, 256, 128, 64, 32, 16};
__constant__ int pk_nact[7] = {516, 256, 128, 64, 32, 16, 2};

struct WPtrs { const float* W[7]; };

__global__ void pack_weights(WPtrs wp, u16* __restrict__ out)
{
    const int gid = blockIdx.x * blockDim.x + threadIdx.x;
    if (gid >= 458 * 64) return;
    const int f    = gid >> 6;
    const int lane = gid & 63;
    int l = 0;
    while (l < 6 && f >= pk_base[l + 1]) ++l;
    const int r    = f - pk_base[l];
    const int ks   = pk_ks[l];
    const int nt   = r / ks;
    const int s    = r % ks;
    const int n    = nt * 32 + (lane & 31);
    const int k0   = s * 16 + (lane >> 5) * 8;
    const int khid = pk_khs[l] * 16;
    const int kact = pk_kact[l];
    const int nact = pk_nact[l];
    const float* W = wp.W[l];

    union { short8 v; u16 e[8]; } frag;
#pragma unroll
    for (int j = 0; j < 8; ++j) {
        const int k = k0 + j;
        float v = 0.0f;
        if (n < nact) {
            if (k < khid) {
                if (k < kact) v = W[k * nact + n];
            } else if (l < 6) {
                const int xr = k - khid;
                if (xr < 37) v = W[(kact + xr) * nact + n];
            }
        }
        frag.e[j] = (u16)f2bf(v);
    }
    *(short8*)(out + (size_t)gid * 8) = frag.v;
}

// ---------------------------------------------------------------------------
// One MLP layer. Unit = (NG n-tiles) x (MS m-tiles of 32 points).
// PREB layers (read buf, write buf in place): exactly one unit per wave,
// k-loop -> __syncthreads -> epilogue write. Non-PREB (L0: reads xin only;
// L6: writes global): units strided over waves, no internal barrier.
// B fragments prefetched through a register ring of PFD k-steps.
// A: A[m=lane&31][k=(lane>>5)*8+j]; B packed; D: col=lane&31,
// row=(reg&3)+8*(reg>>2)+4*(lane>>5)  [m74/m101].
// ---------------------------------------------------------------------------
template<int KHS, int NT, int NG, int MS, int NACT, int LBASE,
         bool XIN, bool RELU, bool GOUT, bool PREB>
__device__ __forceinline__ void mlayer(const u16* __restrict__ wpack,
                                       const float* __restrict__ bias,
                                       u16* __restrict__ s_act,
                                       float* __restrict__ gout, int p0,
                                       int wave, int lane)
{
    constexpr int KS    = KHS + (XIN ? 3 : 0);
    constexpr int NGRP  = (NT + NG - 1) / NG;
    constexpr int MGRP  = 2 / MS;
    constexpr int UNITS = NGRP * MGRP;
    constexpr int PFD   = (KS > 8) ? 4 : 2;      // B-prefetch depth (k-steps)
    const int nl   = lane & 31;
    const int half = lane >> 5;

    const int uend  = PREB ? (wave < UNITS ? wave + 1 : wave) : UNITS;

    for (int u = wave; u < (PREB ? (wave < UNITS ? wave + 1 : wave) : UNITS);
         u += NWAVES) {
        const int gn = u % NGRP;
        const int gm = u / NGRP;
        const int n0 = gn * NG;
        const int m0 = gm * MS;

        const u16* arow[MS];
#pragma unroll
        for (int m = 0; m < MS; ++m)
            arow[m] = s_act + ((m0 + m) * 32 + nl) * SROW + half * 8;

        f32x16 acc[NG][MS];
#pragma unroll
        for (int t = 0; t < NG; ++t)
#pragma unroll
            for (int m = 0; m < MS; ++m)
                acc[t][m] = (f32x16)(0.0f);

        // ---- B-prefetch ring ----
        short8 bq[PFD][NG];
#pragma unroll
        for (int i = 0; i < PFD && i < KS; ++i)
#pragma unroll
            for (int t = 0; t < NG; ++t) {
                const int nt = n0 + t;
                if ((NT % NG) && nt >= NT) break;
                bq[i][t] = *(const short8*)(wpack +
                        ((size_t)(LBASE + nt * KS + i) << 9) + lane * 8);
            }

#pragma unroll
        for (int s = 0; s < KS; ++s) {
            short8 bc[NG];
#pragma unroll
            for (int t = 0; t < NG; ++t) bc[t] = bq[s % PFD][t];
            if (s + PFD < KS) {
#pragma unroll
                for (int t = 0; t < NG; ++t) {
                    const int nt = n0 + t;
                    if ((NT % NG) && nt >= NT) break;
                    bq[s % PFD][t] = *(const short8*)(wpack +
                            ((size_t)(LBASE + nt * KS + (s + PFD)) << 9) + lane * 8);
                }
            }
            const int ab = (s < KHS) ? (BUF_OFF + s * 16)
                                     : ((s - KHS) * 16);
            short8 a[MS];
#pragma unroll
            for (int m = 0; m < MS; ++m)
                a[m] = *(const short8*)(arow[m] + ab);
#pragma unroll
            for (int t = 0; t < NG; ++t) {
                const int nt = n0 + t;
                if ((NT % NG) && nt >= NT) break;
#pragma unroll
                for (int m = 0; m < MS; ++m)
                    acc[t][m] = __builtin_amdgcn_mfma_f32_32x32x16_bf16(a[m], bc[t], acc[t][m], 0, 0, 0);
            }
        }

        if (PREB) __syncthreads();   // uniform: every wave has exactly <=1 unit,
                                     // and inactive waves sync below.

        // ---- epilogue ----
#pragma unroll
        for (int t = 0; t < NG; ++t) {
            const int nt = n0 + t;
            if ((NT % NG) && nt >= NT) break;
            const int n = nt * 32 + nl;
            const float bv = (n < NACT) ? bias[n] : 0.0f;
#pragma unroll
            for (int m = 0; m < MS; ++m) {
#pragma unroll
                for (int q = 0; q < 4; ++q) {
#pragma unroll
                    for (int r = 0; r < 4; ++r) {
                        float v = acc[t][m][q * 4 + r] + bv;
                        if (RELU) v = fmaxf(v, 0.0f);
                        const int pt = (m0 + m) * 32 + q * 8 + half * 4 + r;
                        if (GOUT) {
                            if (nl < 2) gout[(size_t)(p0 + pt) * 2 + nl] = v;
                        } else {
                            // neighbor-lane value via DPP quad_perm(1,0,3,2)
                            const int vi = __builtin_bit_cast(int, v);
                            const int oi = __builtin_amdgcn_update_dpp(
                                               0, vi, 0xB1, 0xF, 0xF, true);
                            const float ov = __builtin_bit_cast(float, oi);
                            const u32 dw = f2bf(v) | (f2bf(ov) << 16);
                            if (!(nl & 1) && n < NACT)
                                *(u32*)(s_act + pt * SROW + BUF_OFF + n) = dw;
                        }
                    }
                }
            }
        }
    }
    if (PREB && wave >= UNITS) __syncthreads();   // idle waves join the barrier
    (void)uend;
}

struct MainParams {
    const float* lr;     // [B,2,64,64]
    const float* ctx;    // [B,32,64,64]
    const float* eps;    // [B,64,64]
    const float* coord;  // [B,N,2]
    const float* Bb[7];  // biases (fp32)
    const u16*   wpack;  // packed bf16 weights in d_ws
    float*       out;    // [B,N,2]
};

__global__ __launch_bounds__(NTH, 4)
void cont_decoder_mfma(MainParams p)
{
    extern __shared__ u16 s_act[];         // MPTS*SROW bf16 = 76032 B
    __shared__ int   s_x0[MPTS], s_y0[MPTS];
    __shared__ float s_wx[MPTS], s_wy[MPTS];

    const int tid  = threadIdx.x;
    const int wave = tid >> 6;
    const int lane = tid & 63;
    const int p0   = blockIdx.x * MPTS;
    const int b    = p0 >> 14;             // 16384 points per batch

    // ---- zero poison guards: xin[37,48) and buf cols [516,544) ----
    for (int i = tid; i < MPTS * 39; i += NTH) {
        const int pt = i / 39, c = i % 39;
        const int col = (c < 11) ? (37 + c) : (BUF_OFF + 516 + (c - 11));
        s_act[pt * SROW + col] = 0;
    }

    // ---- bilinear params + coord features ----
    if (tid < MPTS) {
        const int pt = p0 + tid;
        const float cx = p.coord[2 * pt];
        const float cy = p.coord[2 * pt + 1];
        const float gx = (cx + 1.0f) * 32.0f - 0.5f;   // align_corners=False
        const float gy = (cy + 1.0f) * 32.0f - 0.5f;
        const float fx0 = floorf(gx), fy0 = floorf(gy);
        s_x0[tid] = (int)fx0;
        s_y0[tid] = (int)fy0;
        s_wx[tid] = gx - fx0;
        s_wy[tid] = gy - fy0;
        s_act[tid * SROW + 32] = (u16)f2bf(cx);
        s_act[tid * SROW + 33] = (u16)f2bf(cy);
    }
    __syncthreads();

    // ---- sample 35 channels/point (ref swaps spatial axes: val = g[b,c,x,y]) ----
    for (int idx = tid; idx < MPTS * 35; idx += NTH) {
        const int t = idx / 35;
        const int c = idx % 35;
        const float* base;
        int col;
        if (c < 32)      { base = p.ctx + (size_t)(b * 32 + c) * 4096;       col = c; }
        else if (c < 34) { base = p.lr  + (size_t)(b * 2 + (c - 32)) * 4096; col = 34 + (c - 32); }
        else             { base = p.eps + (size_t)b * 4096;                   col = 36; }

        const int   x0 = s_x0[t], y0 = s_y0[t];
        const float wx = s_wx[t], wy = s_wy[t];
        const int x1 = x0 + 1, y1 = y0 + 1;
        const bool xv0 = (x0 >= 0) & (x0 < 64);
        const bool xv1 = (x1 >= 0) & (x1 < 64);
        const bool yv0 = (y0 >= 0) & (y0 < 64);
        const bool yv1 = (y1 >= 0) & (y1 < 64);
        const int xc0 = min(max(x0, 0), 63), xc1 = min(max(x1, 0), 63);
        const int yc0 = min(max(y0, 0), 63), yc1 = min(max(y1, 0), 63);

        const float w00 = (1.0f - wx) * (1.0f - wy) * ((xv0 && yv0) ? 1.0f : 0.0f);
        const float w10 = wx * (1.0f - wy)          * ((xv1 && yv0) ? 1.0f : 0.0f);
        const float w01 = (1.0f - wx) * wy          * ((xv0 && yv1) ? 1.0f : 0.0f);
        const float w11 = wx * wy                   * ((xv1 && yv1) ? 1.0f : 0.0f);

        const float val = w00 * base[xc0 * 64 + yc0]
                        + w10 * base[xc1 * 64 + yc0]
                        + w01 * base[xc0 * 64 + yc1]
                        + w11 * base[xc1 * 64 + yc1];
        s_act[t * SROW + col] = (u16)f2bf(val);
    }
    __syncthreads();

    // ---- MLP (in-place buf; PREB layers barrier between k-loop & write) ----
    //       KHS  NT  NG MS NACT LBASE  XIN    RELU   GOUT   PREB
    mlayer<  0,  17, 2, 2, 516, 0,     true,  true,  false, false>(p.wpack, p.Bb[0], s_act, nullptr, p0, wave, lane);
    __syncthreads();
    mlayer< 34,   8, 1, 2, 256, 51,    true,  true,  false, true >(p.wpack, p.Bb[1], s_act, nullptr, p0, wave, lane);
    __syncthreads();
    mlayer< 16,   4, 1, 1, 128, 347,   true,  true,  false, true >(p.wpack, p.Bb[2], s_act, nullptr, p0, wave, lane);
    __syncthreads();
    mlayer<  8,   2, 1, 1,  64, 423,   true,  true,  false, true >(p.wpack, p.Bb[3], s_act, nullptr, p0, wave, lane);
    __syncthreads();
    mlayer<  4,   1, 1, 1,  32, 445,   true,  true,  false, true >(p.wpack, p.Bb[4], s_act, nullptr, p0, wave, lane);
    __syncthreads();
    mlayer<  2,   1, 1, 1,  16, 452,   true,  true,  false, true >(p.wpack, p.Bb[5], s_act, nullptr, p0, wave, lane);
    __syncthreads();
    mlayer<  1,   1, 1, 1,   2, 457,   false, false, true,  false>(p.wpack, p.Bb[6], s_act, p.out,   p0, wave, lane);
}

extern "C" void kernel_launch(void* const* d_in, const int* in_sizes, int n_in,
                              void* d_out, int out_size, void* d_ws, size_t ws_size,
                              hipStream_t stream)
{
    WPtrs wp;
    for (int l = 0; l < 7; ++l) wp.W[l] = (const float*)d_in[4 + 2 * l];

    MainParams p;
    p.lr    = (const float*)d_in[0];
    p.ctx   = (const float*)d_in[1];
    p.eps   = (const float*)d_in[2];
    p.coord = (const float*)d_in[3];
    for (int l = 0; l < 7; ++l) p.Bb[l] = (const float*)d_in[5 + 2 * l];
    p.wpack = (const u16*)d_ws;
    p.out   = (float*)d_out;

    // Opt in to >64 KB dynamic LDS (idempotent; capture-safe).
    hipFuncSetAttribute((const void*)cont_decoder_mfma,
                        hipFuncAttributeMaxDynamicSharedMemorySize, LDSBYTES);

    hipLaunchKernelGGL(pack_weights, dim3((458 * 64 + 255) / 256), dim3(256), 0, stream, wp, (u16*)d_ws);
    hipLaunchKernelGGL(cont_decoder_mfma, dim3(GRIDX), dim3(NTH), LDSBYTES, stream, p);
}

// Round 7
// 254.649 us; speedup vs baseline: 1.5170x; 1.5170x over previous
//
#include <hip/hip_runtime.h>

// ============================================================================
// ContDecoder on MI355X — round 7: 32x32x16, MPTS=32, 2 blocks/CU.
//
// R6 failed on accumulator spill (WRITE_SIZE 300 MB) from acc-across-barrier
// + manual prefetch ring. R7 reverts to the clean R5 k-loop and gets latency
// hiding from CU-level TLP instead: 32-point blocks (one m-tile), 8 waves,
// 54.8 KB LDS -> 2 co-resident blocks/CU (16 waves/CU), whose barrier phases
// interleave. L1 = 8 units for 8 waves, 16 acc VGPRs/wave -> compiler has
// headroom (cap 128) to pipeline B-loads itself.
//
// LDS per point (bf16): [hA 0..544 | hB 544..800 | xin 800..848], SROW=856.
// Chain: xin(37p48) ->W0-> hA(516p544) ->W1-> hB(256) ->W2-> hA(128)
//   ->W3-> hB(64) ->W4-> hA(32) ->W5-> hB(16p32) ->W6-> out(2).
// Pad rows of packed W are zero and pad neurons get zero bias => exact
// zeros; stale LDS is never read. Epilogue: DPP lane-pair -> ds_write_b32.
// ============================================================================

#define NTH     512
#define NWAVES  8
#define MPTS    32               // one 32-point m-tile
#define SROW    856
#define HA_OFF  0
#define HB_OFF  544
#define XIN_OFF 800
#define NPOINTS (8 * 16384)
#define GRIDX   (NPOINTS / MPTS)     // 4096 blocks
#define LDSBYTES (MPTS * SROW * 2)   // 54784 B

typedef short          short8 __attribute__((ext_vector_type(8)));
typedef float          f32x16 __attribute__((ext_vector_type(16)));
typedef unsigned short u16;
typedef unsigned int   u32;

__device__ __forceinline__ u32 f2bf(float f) {
    u32 u = __builtin_bit_cast(u32, f);
    u += 0x7fffu + ((u >> 16) & 1u);        // round-to-nearest-even
    return u >> 16;
}

// ---------------------------------------------------------------------------
// Packed-weight geometry: 1KB fragments of 512 bf16. Fragment (l, nt, s):
// lane holds W[k = s*16 + (lane>>5)*8 + j][n = nt*32 + (lane&31)], j=0..7.
//   l : KHS  KS  NT   frag_base
//   0 :  0    3  17      0       (xin-only, K=48)
//   1 : 34   37   8     51
//   2 : 16   19   4    347
//   3 :  8   11   2    423
//   4 :  4    7   1    445
//   5 :  2    5   1    452
//   6 :  1    1   1    457     total 458 frags = 458 KB in d_ws
// ---------------------------------------------------------------------------
__constant__ int pk_base[8] = {0, 51, 347, 423, 445, 452, 457, 458};
__constant__ int pk_ks[7]   = {3, 37, 19, 11, 7, 5, 1};
__constant__ int pk_khs[7]  = {0, 34, 16, 8, 4, 2, 1};
__constant__ int pk_kact[7] = {0, 516, 256, 128, 64, 32, 16};
__constant__ int pk_nact[7] = {516, 256, 128, 64, 32, 16, 2};

struct WPtrs { const float* W[7]; };

__global__ void pack_weights(WPtrs wp, u16* __restrict__ out)
{
    const int gid = blockIdx.x * blockDim.x + threadIdx.x;
    if (gid >= 458 * 64) return;
    const int f    = gid >> 6;
    const int lane = gid & 63;
    int l = 0;
    while (l < 6 && f >= pk_base[l + 1]) ++l;
    const int r    = f - pk_base[l];
    const int ks   = pk_ks[l];
    const int nt   = r / ks;
    const int s    = r % ks;
    const int n    = nt * 32 + (lane & 31);
    const int k0   = s * 16 + (lane >> 5) * 8;
    const int khid = pk_khs[l] * 16;
    const int kact = pk_kact[l];
    const int nact = pk_nact[l];
    const float* W = wp.W[l];

    union { short8 v; u16 e[8]; } frag;
#pragma unroll
    for (int j = 0; j < 8; ++j) {
        const int k = k0 + j;
        float v = 0.0f;
        if (n < nact) {
            if (k < khid) {
                if (k < kact) v = W[k * nact + n];
            } else if (l < 6) {
                const int xr = k - khid;
                if (xr < 37) v = W[(kact + xr) * nact + n];
            }
        }
        frag.e[j] = (u16)f2bf(v);
    }
    *(short8*)(out + (size_t)gid * 8) = frag.v;
}

// ---------------------------------------------------------------------------
// One MLP layer on the 32-point tile. Unit = NG n-tiles; units strided over
// 8 waves. Per k-step: 1 A ds_read_b128 + NG B global loads + NG MFMA.
// A: A[m=lane&31][k=(lane>>5)*8+j]; B packed; D: col(n)=lane&31,
// row(pt)=(reg&3)+8*(reg>>2)+4*(lane>>5)  [m74/m101].
// Epilogue: DPP quad_perm pairs neurons (n,n+1) -> even lanes ds_write_b32.
// ---------------------------------------------------------------------------
template<int KHS, int HSEG, int OSEG, int NT, int NG, int NACT,
         int LBASE, bool XIN, bool RELU, bool GOUT>
__device__ __forceinline__ void mlayer(const u16* __restrict__ wpack,
                                       const float* __restrict__ bias,
                                       u16* __restrict__ s_act,
                                       float* __restrict__ gout, int p0,
                                       int wave, int lane)
{
    constexpr int KS    = KHS + (XIN ? 3 : 0);
    constexpr int NGRP  = (NT + NG - 1) / NG;
    const int nl   = lane & 31;
    const int half = lane >> 5;
    const u16* arow = s_act + nl * SROW + half * 8;

    for (int g = wave; g < NGRP; g += NWAVES) {
        const int n0 = g * NG;

        f32x16 acc[NG];
#pragma unroll
        for (int t = 0; t < NG; ++t)
            acc[t] = (f32x16)(0.0f);

#pragma unroll
        for (int s = 0; s < KS; ++s) {
            const int ab = (s < KHS) ? (HSEG + s * 16)
                                     : (XIN_OFF + (s - KHS) * 16);
            const short8 a = *(const short8*)(arow + ab);
#pragma unroll
            for (int t = 0; t < NG; ++t) {
                const int nt = n0 + t;
                if ((NT % NG) && nt >= NT) break;
                const short8 b = *(const short8*)(wpack +
                        ((size_t)(LBASE + nt * KS + s) << 9) + lane * 8);
                acc[t] = __builtin_amdgcn_mfma_f32_32x32x16_bf16(a, b, acc[t], 0, 0, 0);
            }
        }

#pragma unroll
        for (int t = 0; t < NG; ++t) {
            const int nt = n0 + t;
            if ((NT % NG) && nt >= NT) break;
            const int n = nt * 32 + nl;
            const float bv = (n < NACT) ? bias[n] : 0.0f;
#pragma unroll
            for (int q = 0; q < 4; ++q) {
#pragma unroll
                for (int r = 0; r < 4; ++r) {
                    float v = acc[t][q * 4 + r] + bv;
                    if (RELU) v = fmaxf(v, 0.0f);
                    const int pt = q * 8 + half * 4 + r;
                    if (GOUT) {
                        if (nl < 2) gout[(size_t)(p0 + pt) * 2 + nl] = v;
                    } else {
                        // neighbor-lane value via DPP quad_perm(1,0,3,2)
                        const int vi = __builtin_bit_cast(int, v);
                        const int oi = __builtin_amdgcn_update_dpp(
                                           0, vi, 0xB1, 0xF, 0xF, true);
                        const float ov = __builtin_bit_cast(float, oi);
                        const u32 dw = f2bf(v) | (f2bf(ov) << 16);
                        if (!(nl & 1))   // even neuron lanes write the pair
                            *(u32*)(s_act + pt * SROW + OSEG + n) = dw;
                    }
                }
            }
        }
    }
}

struct MainParams {
    const float* lr;     // [B,2,64,64]
    const float* ctx;    // [B,32,64,64]
    const float* eps;    // [B,64,64]
    const float* coord;  // [B,N,2]
    const float* Bb[7];  // biases (fp32)
    const u16*   wpack;  // packed bf16 weights in d_ws
    float*       out;    // [B,N,2]
};

__global__ __launch_bounds__(NTH, 4)
void cont_decoder_mfma(MainParams p)
{
    extern __shared__ u16 s_act[];         // MPTS*SROW bf16 = 54784 B
    __shared__ int   s_x0[MPTS], s_y0[MPTS];
    __shared__ float s_wx[MPTS], s_wy[MPTS];

    const int tid  = threadIdx.x;
    const int wave = tid >> 6;
    const int lane = tid & 63;
    const int p0   = blockIdx.x * MPTS;
    const int b    = p0 >> 14;             // 16384 points per batch

    // ---- zero xin pad cols [37..48) ----
    for (int i = tid; i < MPTS * 11; i += NTH) {
        const int pt = i / 11, c = 37 + i % 11;
        s_act[pt * SROW + XIN_OFF + c] = 0;
    }

    // ---- bilinear params + coord features ----
    if (tid < MPTS) {
        const int pt = p0 + tid;
        const float cx = p.coord[2 * pt];
        const float cy = p.coord[2 * pt + 1];
        const float gx = (cx + 1.0f) * 32.0f - 0.5f;   // align_corners=False
        const float gy = (cy + 1.0f) * 32.0f - 0.5f;
        const float fx0 = floorf(gx), fy0 = floorf(gy);
        s_x0[tid] = (int)fx0;
        s_y0[tid] = (int)fy0;
        s_wx[tid] = gx - fx0;
        s_wy[tid] = gy - fy0;
        s_act[tid * SROW + XIN_OFF + 32] = (u16)f2bf(cx);
        s_act[tid * SROW + XIN_OFF + 33] = (u16)f2bf(cy);
    }
    __syncthreads();

    // ---- sample 35 channels/point (ref swaps spatial axes: val = g[b,c,x,y]) ----
    for (int idx = tid; idx < MPTS * 35; idx += NTH) {
        const int t = idx / 35;
        const int c = idx % 35;
        const float* base;
        int col;
        if (c < 32)      { base = p.ctx + (size_t)(b * 32 + c) * 4096;       col = c; }
        else if (c < 34) { base = p.lr  + (size_t)(b * 2 + (c - 32)) * 4096; col = 34 + (c - 32); }
        else             { base = p.eps + (size_t)b * 4096;                   col = 36; }

        const int   x0 = s_x0[t], y0 = s_y0[t];
        const float wx = s_wx[t], wy = s_wy[t];
        const int x1 = x0 + 1, y1 = y0 + 1;
        const bool xv0 = (x0 >= 0) & (x0 < 64);
        const bool xv1 = (x1 >= 0) & (x1 < 64);
        const bool yv0 = (y0 >= 0) & (y0 < 64);
        const bool yv1 = (y1 >= 0) & (y1 < 64);
        const int xc0 = min(max(x0, 0), 63), xc1 = min(max(x1, 0), 63);
        const int yc0 = min(max(y0, 0), 63), yc1 = min(max(y1, 0), 63);

        const float w00 = (1.0f - wx) * (1.0f - wy) * ((xv0 && yv0) ? 1.0f : 0.0f);
        const float w10 = wx * (1.0f - wy)          * ((xv1 && yv0) ? 1.0f : 0.0f);
        const float w01 = (1.0f - wx) * wy          * ((xv0 && yv1) ? 1.0f : 0.0f);
        const float w11 = wx * wy                   * ((xv1 && yv1) ? 1.0f : 0.0f);

        const float val = w00 * base[xc0 * 64 + yc0]
                        + w10 * base[xc1 * 64 + yc0]
                        + w01 * base[xc0 * 64 + yc1]
                        + w11 * base[xc1 * 64 + yc1];
        s_act[t * SROW + XIN_OFF + col] = (u16)f2bf(val);
    }
    __syncthreads();

    // ---- MLP ----
    //       KHS  HSEG    OSEG    NT  NG NACT LBASE  XIN    RELU   GOUT
    mlayer<  0,  HA_OFF, HA_OFF, 17, 2, 516, 0,     true,  true,  false>(p.wpack, p.Bb[0], s_act, nullptr, p0, wave, lane);
    __syncthreads();
    mlayer< 34,  HA_OFF, HB_OFF,  8, 1, 256, 51,    true,  true,  false>(p.wpack, p.Bb[1], s_act, nullptr, p0, wave, lane);
    __syncthreads();
    mlayer< 16,  HB_OFF, HA_OFF,  4, 1, 128, 347,   true,  true,  false>(p.wpack, p.Bb[2], s_act, nullptr, p0, wave, lane);
    __syncthreads();
    mlayer<  8,  HA_OFF, HB_OFF,  2, 1,  64, 423,   true,  true,  false>(p.wpack, p.Bb[3], s_act, nullptr, p0, wave, lane);
    __syncthreads();
    mlayer<  4,  HB_OFF, HA_OFF,  1, 1,  32, 445,   true,  true,  false>(p.wpack, p.Bb[4], s_act, nullptr, p0, wave, lane);
    __syncthreads();
    mlayer<  2,  HA_OFF, HB_OFF,  1, 1,  16, 452,   true,  true,  false>(p.wpack, p.Bb[5], s_act, nullptr, p0, wave, lane);
    __syncthreads();
    mlayer<  1,  HB_OFF, 0,       1, 1,   2, 457,   false, false, true >(p.wpack, p.Bb[6], s_act, p.out,   p0, wave, lane);
}

extern "C" void kernel_launch(void* const* d_in, const int* in_sizes, int n_in,
                              void* d_out, int out_size, void* d_ws, size_t ws_size,
                              hipStream_t stream)
{
    WPtrs wp;
    for (int l = 0; l < 7; ++l) wp.W[l] = (const float*)d_in[4 + 2 * l];

    MainParams p;
    p.lr    = (const float*)d_in[0];
    p.ctx   = (const float*)d_in[1];
    p.eps   = (const float*)d_in[2];
    p.coord = (const float*)d_in[3];
    for (int l = 0; l < 7; ++l) p.Bb[l] = (const float*)d_in[5 + 2 * l];
    p.wpack = (const u16*)d_ws;
    p.out   = (float*)d_out;

    hipFuncSetAttribute((const void*)cont_decoder_mfma,
                        hipFuncAttributeMaxDynamicSharedMemorySize, LDSBYTES);

    hipLaunchKernelGGL(pack_weights, dim3((458 * 64 + 255) / 256), dim3(256), 0, stream, wp, (u16*)d_ws);
    hipLaunchKernelGGL(cont_decoder_mfma, dim3(GRIDX), dim3(NTH), LDSBYTES, stream, p);
}

// Round 8
// 230.423 us; speedup vs baseline: 1.6764x; 1.1051x over previous
//
#include <hip/hip_runtime.h>

// ============================================================================
// ContDecoder on MI355X — round 8: MPTS=64 in-place buffer (2 blocks/CU)
// + statically-indexed chunked B double-buffer.
//
// Model (fits R2–R7): block time is latency-serial B(L2 ~300cyc)->MFMA
// k-steps; compiler never pipelines (VGPR 32 in R7). Fixes:
//  * MPTS=64, B shared across both 32-pt m-tiles in-wave -> halves B traffic
//    (TCP floor 49->24 us/CU) and halves block count.
//  * In-place activation buffer [buf 0..544 | xin 544..592], SROW=592 ->
//    75.75 KB LDS -> 2 blocks/CU (16 waves). In-place layers: k-loop ->
//    barrier -> epilogue-overwrite (acc in regs across barrier).
//  * kloop: CH=4 chunked double-buffered B with ALL indices constexpr
//    (R6's spill = dynamic ring index -> scratch; this stays in VGPRs).
//    Loads of chunk c+1 issue before compute of chunk c -> ~300cyc/chunk.
//  * Tail L4-L6: single wave, straight-line, zero barriers; other waves done.
//
// Zero-padding invariants: packed-W pad rows/cols are 0, pad neurons get
// bias 0 -> exact zeros; xin[37..48) zeroed at init; h0 pad [516..544)
// written 0 by the nt=16 unit. Epilogue: DPP pair -> ds_write_b32.
// ============================================================================

#define NTH     512
#define NWAVES  8
#define MPTS    64               // 2 m-tiles of 32 points
#define SROW    592              // bf16 elems per point row
#define XIN_OFF 544
#define NPOINTS (8 * 16384)
#define GRIDX   (NPOINTS / MPTS)     // 2048 blocks
#define LDSBYTES (MPTS * SROW * 2)   // 75776 B

typedef short          short8 __attribute__((ext_vector_type(8)));
typedef float          f32x16 __attribute__((ext_vector_type(16)));
typedef unsigned short u16;
typedef unsigned int   u32;

__device__ __forceinline__ u32 f2bf(float f) {
    u32 u = __builtin_bit_cast(u32, f);
    u += 0x7fffu + ((u >> 16) & 1u);        // round-to-nearest-even
    return u >> 16;
}

// ---------------------------------------------------------------------------
// Packed-weight geometry: 1KB fragments of 512 bf16. Fragment (l, nt, s):
// lane holds W[k = s*16 + (lane>>5)*8 + j][n = nt*32 + (lane&31)], j=0..7.
//   l : KHS  KS  NT   frag_base
//   0 :  0    3  17      0       (xin-only, K=48)
//   1 : 34   37   8     51
//   2 : 16   19   4    347
//   3 :  8   11   2    423
//   4 :  4    7   1    445
//   5 :  2    5   1    452
//   6 :  1    1   1    457     total 458 frags = 458 KB in d_ws
// ---------------------------------------------------------------------------
__constant__ int pk_base[8] = {0, 51, 347, 423, 445, 452, 457, 458};
__constant__ int pk_ks[7]   = {3, 37, 19, 11, 7, 5, 1};
__constant__ int pk_khs[7]  = {0, 34, 16, 8, 4, 2, 1};
__constant__ int pk_kact[7] = {0, 516, 256, 128, 64, 32, 16};
__constant__ int pk_nact[7] = {516, 256, 128, 64, 32, 16, 2};

struct WPtrs { const float* W[7]; };

__global__ void pack_weights(WPtrs wp, u16* __restrict__ out)
{
    const int gid = blockIdx.x * blockDim.x + threadIdx.x;
    if (gid >= 458 * 64) return;
    const int f    = gid >> 6;
    const int lane = gid & 63;
    int l = 0;
    while (l < 6 && f >= pk_base[l + 1]) ++l;
    const int r    = f - pk_base[l];
    const int ks   = pk_ks[l];
    const int nt   = r / ks;
    const int s    = r % ks;
    const int n    = nt * 32 + (lane & 31);
    const int k0   = s * 16 + (lane >> 5) * 8;
    const int khid = pk_khs[l] * 16;
    const int kact = pk_kact[l];
    const int nact = pk_nact[l];
    const float* W = wp.W[l];

    union { short8 v; u16 e[8]; } frag;
#pragma unroll
    for (int j = 0; j < 8; ++j) {
        const int k = k0 + j;
        float v = 0.0f;
        if (n < nact) {
            if (k < khid) {
                if (k < kact) v = W[k * nact + n];
            } else if (l < 6) {
                const int xr = k - khid;
                if (xr < 37) v = W[(kact + xr) * nact + n];
            }
        }
        frag.e[j] = (u16)f2bf(v);
    }
    *(short8*)(out + (size_t)gid * 8) = frag.v;
}

// ---------------------------------------------------------------------------
// Chunked k-loop: CH=4 double-buffered B fragments, all indices constexpr
// after unroll (registers, no scratch). Per k-step: 2 A ds_read_b128 (both
// m-tiles) + 1 B load + 2 MFMA. A: A[m=lane&31][k=(lane>>5)*8+j]; B packed;
// D: col=lane&31, row=(reg&3)+8*(reg>>2)+4*(lane>>5)  [m74/m101].
// ---------------------------------------------------------------------------
template<int KHS, int KS, int LBASE>
__device__ __forceinline__ void kloop(const u16* __restrict__ wpack,
                                      const u16* __restrict__ s_act,
                                      int nt, int lane,
                                      f32x16& acc0, f32x16& acc1)
{
    constexpr int CH   = 4;
    constexpr int NCHK = (KS + CH - 1) / CH;
    const int nl   = lane & 31;
    const int half = lane >> 5;
    const u16* a0p = s_act + (nl * SROW + half * 8);
    const u16* a1p = s_act + ((32 + nl) * SROW + half * 8);
    const u16* wb  = wpack + (((size_t)(LBASE + nt * KS)) << 9) + lane * 8;

    short8 bq[2][CH];
#pragma unroll
    for (int i = 0; i < CH; ++i)
        if (i < KS) bq[0][i] = *(const short8*)(wb + ((size_t)i << 9));

#pragma unroll
    for (int c = 0; c < NCHK; ++c) {
        const int cur = c & 1;                 // folds to constant per c
#pragma unroll
        for (int i = 0; i < CH; ++i) {
            const int s = (c + 1) * CH + i;
            if (s < KS)
                bq[cur ^ 1][i] = *(const short8*)(wb + ((size_t)s << 9));
        }
#pragma unroll
        for (int i = 0; i < CH; ++i) {
            const int s = c * CH + i;
            if (s < KS) {
                const int ab = (s < KHS) ? (s * 16)
                                         : (XIN_OFF + (s - KHS) * 16);
                const short8 a0 = *(const short8*)(a0p + ab);
                const short8 a1 = *(const short8*)(a1p + ab);
                acc0 = __builtin_amdgcn_mfma_f32_32x32x16_bf16(a0, bq[cur][i], acc0, 0, 0, 0);
                acc1 = __builtin_amdgcn_mfma_f32_32x32x16_bf16(a1, bq[cur][i], acc1, 0, 0, 0);
            }
        }
    }
}

// Epilogue: bias + ReLU, DPP quad_perm(1,0,3,2) pairs neurons (n,n+1),
// even lanes write one dword -> conflict-free. GOUT: final global write.
template<int NACT, bool RELU, bool GOUT>
__device__ __forceinline__ void epilogue(int nt, int lane,
                                         const float* __restrict__ bias,
                                         const f32x16& acc0, const f32x16& acc1,
                                         u16* __restrict__ s_act,
                                         float* __restrict__ gout, int p0)
{
    const int nl   = lane & 31;
    const int half = lane >> 5;
    const int n    = nt * 32 + nl;
    const float bv = (n < NACT) ? bias[n] : 0.0f;
#pragma unroll
    for (int m = 0; m < 2; ++m) {
        const f32x16& acc = m ? acc1 : acc0;
#pragma unroll
        for (int q = 0; q < 4; ++q) {
#pragma unroll
            for (int r = 0; r < 4; ++r) {
                float v = acc[q * 4 + r] + bv;
                if (RELU) v = fmaxf(v, 0.0f);
                const int pt = m * 32 + q * 8 + half * 4 + r;
                if (GOUT) {
                    if (nl < 2) gout[(size_t)(p0 + pt) * 2 + nl] = v;
                } else {
                    const int vi = __builtin_bit_cast(int, v);
                    const int oi = __builtin_amdgcn_update_dpp(
                                       0, vi, 0xB1, 0xF, 0xF, true);
                    const float ov = __builtin_bit_cast(float, oi);
                    const u32 dw = f2bf(v) | (f2bf(ov) << 16);
                    if (!(nl & 1))
                        *(u32*)(s_act + pt * SROW + n) = dw;
                }
            }
        }
    }
}

// In-place layer: k-loop (read buf) -> barrier -> overwrite buf[0..NACTpad).
// NT <= NWAVES: wave w handles n-tile w; idle waves just hit the barriers.
template<int KHS, int KS, int NT, int NACT, int LBASE>
__device__ __forceinline__ void mlayer_ip(const u16* __restrict__ wpack,
                                          const float* __restrict__ bias,
                                          u16* __restrict__ s_act,
                                          int wave, int lane)
{
    f32x16 acc0 = (f32x16)(0.0f), acc1 = (f32x16)(0.0f);
    if (wave < NT)
        kloop<KHS, KS, LBASE>(wpack, s_act, wave, lane, acc0, acc1);
    __syncthreads();
    if (wave < NT)
        epilogue<NACT, true, false>(wave, lane, bias, acc0, acc1,
                                    s_act, nullptr, 0);
    __syncthreads();
}

struct MainParams {
    const float* lr;     // [B,2,64,64]
    const float* ctx;    // [B,32,64,64]
    const float* eps;    // [B,64,64]
    const float* coord;  // [B,N,2]
    const float* Bb[7];  // biases (fp32)
    const u16*   wpack;  // packed bf16 weights in d_ws
    float*       out;    // [B,N,2]
};

__global__ __launch_bounds__(NTH, 4)
void cont_decoder_mfma(MainParams p)
{
    extern __shared__ u16 s_act[];   // 64 rows x 592 elems = 75776 B
    const int tid  = threadIdx.x;
    const int wave = tid >> 6;
    const int lane = tid & 63;
    const int p0   = blockIdx.x * MPTS;
    const int b    = p0 >> 14;       // 16384 points per batch

    // ---- fused xin build: f in [0,48) per point; self-contained threads ----
    // cols: 0..31 ctx | 32,33 coord | 34,35 lr | 36 eps | 37..47 zero pad.
    // Ref swaps spatial axes before grid_sample: val = g[b, c, x, y].
    for (int idx = tid; idx < MPTS * 48; idx += NTH) {
        const int t = idx / 48;
        const int f = idx % 48;
        const int pt = p0 + t;
        float val = 0.0f;
        if (f < 37) {
            const float cx = p.coord[2 * pt];
            const float cy = p.coord[2 * pt + 1];
            if (f == 32)      val = cx;
            else if (f == 33) val = cy;
            else {
                const float* base;
                if (f < 32)       base = p.ctx + (size_t)(b * 32 + f) * 4096;
                else if (f < 36)  base = p.lr  + (size_t)(b * 2 + (f - 34)) * 4096;
                else              base = p.eps + (size_t)b * 4096;

                const float gx = (cx + 1.0f) * 32.0f - 0.5f;  // align_corners=False
                const float gy = (cy + 1.0f) * 32.0f - 0.5f;
                const float fx0 = floorf(gx), fy0 = floorf(gy);
                const int   x0 = (int)fx0,   y0 = (int)fy0;
                const float wx = gx - fx0,   wy = gy - fy0;
                const int x1 = x0 + 1, y1 = y0 + 1;
                const bool xv0 = (x0 >= 0) & (x0 < 64);
                const bool xv1 = (x1 >= 0) & (x1 < 64);
                const bool yv0 = (y0 >= 0) & (y0 < 64);
                const bool yv1 = (y1 >= 0) & (y1 < 64);
                const int xc0 = min(max(x0, 0), 63), xc1 = min(max(x1, 0), 63);
                const int yc0 = min(max(y0, 0), 63), yc1 = min(max(y1, 0), 63);

                const float w00 = (1.0f - wx) * (1.0f - wy) * ((xv0 && yv0) ? 1.0f : 0.0f);
                const float w10 = wx * (1.0f - wy)          * ((xv1 && yv0) ? 1.0f : 0.0f);
                const float w01 = (1.0f - wx) * wy          * ((xv0 && yv1) ? 1.0f : 0.0f);
                const float w11 = wx * wy                   * ((xv1 && yv1) ? 1.0f : 0.0f);

                val = w00 * base[xc0 * 64 + yc0]
                    + w10 * base[xc1 * 64 + yc0]
                    + w01 * base[xc0 * 64 + yc1]
                    + w11 * base[xc1 * 64 + yc1];
            }
        }
        s_act[t * SROW + XIN_OFF + f] = (u16)f2bf(val);
    }
    __syncthreads();

    // ---- L0: xin(48) -> h0(516p544), 17 n-tiles over 8 waves ----
    for (int u = wave; u < 17; u += NWAVES) {
        f32x16 a0 = (f32x16)(0.0f), a1 = (f32x16)(0.0f);
        kloop<0, 3, 0>(p.wpack, s_act, u, lane, a0, a1);
        epilogue<516, true, false>(u, lane, p.Bb[0], a0, a1, s_act, nullptr, 0);
    }
    __syncthreads();

    // ---- L1..L3: in-place buf overwrite ----
    mlayer_ip<34, 37, 8, 256, 51 >(p.wpack, p.Bb[1], s_act, wave, lane);
    mlayer_ip<16, 19, 4, 128, 347>(p.wpack, p.Bb[2], s_act, wave, lane);
    mlayer_ip< 8, 11, 2,  64, 423>(p.wpack, p.Bb[3], s_act, wave, lane);

    // ---- tail L4-L6: single wave, straight-line, no barriers ----
    if (wave == 0) {
        {
            f32x16 a0 = (f32x16)(0.0f), a1 = (f32x16)(0.0f);
            kloop<4, 7, 445>(p.wpack, s_act, 0, lane, a0, a1);
            epilogue<32, true, false>(0, lane, p.Bb[4], a0, a1, s_act, nullptr, 0);
        }
        {
            f32x16 a0 = (f32x16)(0.0f), a1 = (f32x16)(0.0f);
            kloop<2, 5, 452>(p.wpack, s_act, 0, lane, a0, a1);
            epilogue<16, true, false>(0, lane, p.Bb[5], a0, a1, s_act, nullptr, 0);
        }
        {
            f32x16 a0 = (f32x16)(0.0f), a1 = (f32x16)(0.0f);
            kloop<1, 1, 457>(p.wpack, s_act, 0, lane, a0, a1);
            epilogue<2, false, true>(0, lane, p.Bb[6], a0, a1, s_act, p.out, p0);
        }
    }
}

extern "C" void kernel_launch(void* const* d_in, const int* in_sizes, int n_in,
                              void* d_out, int out_size, void* d_ws, size_t ws_size,
                              hipStream_t stream)
{
    WPtrs wp;
    for (int l = 0; l < 7; ++l) wp.W[l] = (const float*)d_in[4 + 2 * l];

    MainParams p;
    p.lr    = (const float*)d_in[0];
    p.ctx   = (const float*)d_in[1];
    p.eps   = (const float*)d_in[2];
    p.coord = (const float*)d_in[3];
    for (int l = 0; l < 7; ++l) p.Bb[l] = (const float*)d_in[5 + 2 * l];
    p.wpack = (const u16*)d_ws;
    p.out   = (float*)d_out;

    hipFuncSetAttribute((const void*)cont_decoder_mfma,
                        hipFuncAttributeMaxDynamicSharedMemorySize, LDSBYTES);

    hipLaunchKernelGGL(pack_weights, dim3((458 * 64 + 255) / 256), dim3(256), 0, stream, wp, (u16*)d_ws);
    hipLaunchKernelGGL(cont_decoder_mfma, dim3(GRIDX), dim3(NTH), LDSBYTES, stream, p);
}